// Round 4
// baseline (214.606 us; speedup 1.0000x reference)
//
#include <hip/hip_runtime.h>
#include <math.h>

// SNN event model: causal conv (K=8) + LIF scan + outputs (I, z, s, logits).
// x (32,1,8192) f32, conv_w (64,1,8) f32, raw_tau (64,) f32.
// out = [I (32*64*8192), z, s, logits (32*8192)] fp32 = 202 MB -> store-BW bound.
//
// Block = 1 wave (64 lanes = 64 features), one (b, 32-step time chunk).
// Warm-up 64 steps from v=0 (alpha <= ~0.74 => decay ~4e-9, below threshold).
// Key structure: NO barrier ever follows a store -> no s_waitcnt vmcnt(0)
// drains. Single flush at kernel end; I is recomputed there directly in the
// store layout (pure conv, no recurrence), so only z needs an LDS transpose
// tile. LDS ~11 KB -> 14 waves/CU (was 9).

#define LL 8192
#define BB 32
#define FF 64
#define KK 8
#define CHUNK 32
#define NCH (LL / CHUNK)            // 256
#define WARM 64
#define NX (WARM + KK - 1 + CHUNK + 1)  // 104

typedef float vfloat4 __attribute__((ext_vector_type(4)));

__global__ __launch_bounds__(64) void snn_kernel(
    const float* __restrict__ x, const float* __restrict__ conv_w,
    const float* __restrict__ raw_tau, float* __restrict__ out)
{
    __shared__ float x_lds[NX];
    __shared__ float w_lds[FF][KK];
    __shared__ float z_tile[FF][CHUNK + 1];   // stride 33: conflict-free

    const int f  = threadIdx.x;               // lane = feature
    const int c  = blockIdx.x;                // time chunk
    const int b  = blockIdx.y;                // batch
    const int t0 = c * CHUNK;
    const int g0 = t0 - WARM - (KK - 1);      // global time of x_lds[0]

    // ---- per-feature constants (fp64 setup, rounded to fp32) ----
    double wd[KK]; double ss = 0.0;
    #pragma unroll
    for (int k = 0; k < KK; ++k) {
        wd[k] = (double)conv_w[f * KK + k];
        ss += wd[k] * wd[k];
    }
    double nrm = sqrt(ss);
    if (nrm < 1e-8) nrm = 1e-8;
    double invn = 1.0 / nrm;
    float wf[KK];
    #pragma unroll
    for (int k = 0; k < KK; ++k) { wf[k] = (float)(wd[k] * invn); w_lds[f][k] = wf[k]; }

    double rt    = (double)raw_tau[f];
    double tau   = log1p(exp(rt)) + 1e-4;     // softplus + eps
    float alpha  = (float)exp(-1.0 / tau);
    float oma    = 1.0f - alpha;

    // ---- stage 20*x into LDS (zero pad out of range) ----
    for (int i = f; i < NX; i += 64) {
        int g = g0 + i;
        x_lds[i] = (g >= 0 && g < LL) ? (20.0f * x[(size_t)b * LL + g]) : 0.0f;
    }
    __syncthreads();                          // no stores outstanding: cheap

    // ---- recurrence with rolling x window (1 LDS read/step) ----
    float xw[KK];
    #pragma unroll
    for (int k = 0; k < KK; ++k) xw[k] = x_lds[k];
    float v = 0.0f;

    #pragma unroll 8
    for (int s = 0; s < WARM; ++s) {
        float acc = 0.0f;
        #pragma unroll
        for (int k = 0; k < KK; ++k) acc = fmaf(wf[k], xw[k], acc);
        float vp = fmaf(alpha, v, oma * acc);
        v = (vp >= 0.25f) ? 0.0f : vp;
        #pragma unroll
        for (int k = 0; k < KK - 1; ++k) xw[k] = xw[k + 1];
        xw[KK - 1] = x_lds[s + KK];
    }
    #pragma unroll 8
    for (int j = 0; j < CHUNK; ++j) {
        float acc = 0.0f;
        #pragma unroll
        for (int k = 0; k < KK; ++k) acc = fmaf(wf[k], xw[k], acc);
        float vp = fmaf(alpha, v, oma * acc);
        z_tile[f][j] = 15.0f * (vp - 0.25f);
        v = (vp >= 0.25f) ? 0.0f : vp;
        #pragma unroll
        for (int k = 0; k < KK - 1; ++k) xw[k] = xw[k + 1];
        xw[KK - 1] = x_lds[WARM + j + KK];    // max 64+31+8 = 103 < NX
    }
    __syncthreads();                          // still no stores outstanding

    // ---- single flush: coalesced NT stores, no barrier after ----
    float* outI  = out;
    float* outZ  = out + (size_t)BB * FF * LL;
    float* outS  = out + (size_t)2 * BB * FF * LL;
    float* outLg = out + (size_t)3 * BB * FF * LL;

    const int r = f >> 3;                     // row within group of 8
    const int q = (f & 7) * 4;                // time offset (16 B aligned)

    float xv[KK + 3];                         // x window for this lane's 4 t's
    #pragma unroll
    for (int m = 0; m < KK + 3; ++m) xv[m] = x_lds[WARM + q + m];

    #pragma unroll
    for (int it = 0; it < 8; ++it) {
        const int fr = it * 8 + r;
        float wl[KK];
        #pragma unroll
        for (int k = 0; k < KK; ++k) wl[k] = w_lds[fr][k];
        vfloat4 vi, vz, vs;
        #pragma unroll
        for (int i = 0; i < 4; ++i) {
            float a = 0.0f;
            #pragma unroll
            for (int k = 0; k < KK; ++k) a = fmaf(wl[k], xv[i + k], a);
            vi[i] = a;                        // I recomputed in store layout
            float zz = z_tile[fr][q + i];
            vz[i] = zz;
            vs[i] = (zz >= 0.0f) ? 1.0f : 0.0f;
        }
        size_t base = ((size_t)b * FF + fr) * LL + t0 + q;
        __builtin_nontemporal_store(vi, (vfloat4*)(outI + base));
        __builtin_nontemporal_store(vz, (vfloat4*)(outZ + base));
        __builtin_nontemporal_store(vs, (vfloat4*)(outS + base));
    }
    if (f < CHUNK) {                          // logits: max over features
        float m = z_tile[0][f];
        #pragma unroll
        for (int ff = 1; ff < FF; ++ff) m = fmaxf(m, z_tile[ff][f]);
        outLg[(size_t)b * LL + t0 + f] = m;
    }
}

extern "C" void kernel_launch(void* const* d_in, const int* in_sizes, int n_in,
                              void* d_out, int out_size, void* d_ws, size_t ws_size,
                              hipStream_t stream) {
    const float* x  = (const float*)d_in[0];
    const float* w  = (const float*)d_in[1];
    const float* rt = (const float*)d_in[2];
    float* out = (float*)d_out;
    dim3 grid(NCH, BB);
    snn_kernel<<<grid, 64, 0, stream>>>(x, w, rt, out);
}